// Round 10
// baseline (442.368 us; speedup 1.0000x reference)
//
#include <hip/hip_runtime.h>
#include <math.h>

// ---------------------------------------------------------------------------
// 3-layer GCN on MI355X.
//   h1 = relu(Ahat @ (x W1) + b1)          gather at F=64
//   h2 = relu((Ahat @ h1) W2 + b2)         reordered: gather at F=64, not 128
//   out = log_softmax(Ahat @ (h2 W3) + b3) gather at F=40
// R10: MEASUREMENT ROUND. Identical to R9 except gemm1 runs 3x (2 scratch +
// 1 real). G = (dur_R10 - dur_R9)/2 gives gemm1's true cost, resolving the
// R6-vs-R7/R8/R9 attribution contradiction (fused 158us vs <113us top-5 bound).
// ---------------------------------------------------------------------------

typedef __attribute__((ext_vector_type(8))) short short8;
typedef __attribute__((ext_vector_type(4))) float f32x4;

__device__ __forceinline__ unsigned short f2bf(float f) {
    unsigned int u = __float_as_uint(f);
    unsigned int r = (u + 0x7fffu + ((u >> 16) & 1u)) >> 16;   // RNE
    return (unsigned short)r;
}
__device__ __forceinline__ float bflo(unsigned int u) { return __uint_as_float(u << 16); }
__device__ __forceinline__ float bfhi(unsigned int u) { return __uint_as_float(u & 0xffff0000u); }

// ---------------- prep: W fragment pack + zero cnt/fillc ----------------
__device__ __forceinline__ void wprep_one(const float* W, unsigned short* out,
                                          int KS, int FOUT, int t) {
    int i = t & 7;
    int l = (t >> 3) & 63;
    int g = t >> 9;
    int ks = g % KS;
    int nt = g / KS;
    int k = ks * 32 + (l >> 4) * 8 + i;
    int c = nt * 16 + (l & 15);
    out[t] = (c < FOUT) ? f2bf(W[(size_t)k * FOUT + c]) : (unsigned short)0;
}

__global__ void prep_kernel(const float* __restrict__ W1, const float* __restrict__ W2,
                            const float* __restrict__ W3,
                            unsigned short* __restrict__ Wf1, unsigned short* __restrict__ Wf2,
                            unsigned short* __restrict__ Wf3,
                            int* __restrict__ cnt, int* __restrict__ fillc, int N) {
    int t = blockIdx.x * 256 + threadIdx.x;
    if (t < 32768)       wprep_one(W1, Wf1, 16, 64, t);
    else if (t < 40960)  wprep_one(W2, Wf2, 2, 128, t - 32768);
    else if (t < 47104)  wprep_one(W3, Wf3, 4, 40, t - 40960);
    if (t < N) cnt[t] = 0;
    else if (t < 2 * N) fillc[t - N] = 0;
}

__global__ void count_kernel(const int* __restrict__ col, int* __restrict__ cnt, int E) {
    int e = blockIdx.x * 256 + threadIdx.x;
    if (e < E) atomicAdd(&cnt[col[e]], 1);
}

// ---------------- scan ----------------
__global__ void scan1_kernel(const int* __restrict__ cnt, int* __restrict__ out,
                             int* __restrict__ bsums, int n) {
    __shared__ int s[1024];
    int i = blockIdx.x * 1024 + threadIdx.x;
    int v = (i < n) ? cnt[i] : 0;
    s[threadIdx.x] = v;
    __syncthreads();
    for (int off = 1; off < 1024; off <<= 1) {
        int t = 0;
        if ((int)threadIdx.x >= off) t = s[threadIdx.x - off];
        __syncthreads();
        if ((int)threadIdx.x >= off) s[threadIdx.x] += t;
        __syncthreads();
    }
    if (i < n) out[i] = s[threadIdx.x] - v;
    if (threadIdx.x == 1023) bsums[blockIdx.x] = s[1023];
}

__global__ void scan2_kernel(int* bsums, int nb) {
    __shared__ int s[128];
    int v = ((int)threadIdx.x < nb) ? bsums[threadIdx.x] : 0;
    s[threadIdx.x] = v;
    __syncthreads();
    for (int off = 1; off < 128; off <<= 1) {
        int t = 0;
        if ((int)threadIdx.x >= off) t = s[threadIdx.x - off];
        __syncthreads();
        if ((int)threadIdx.x >= off) s[threadIdx.x] += t;
        __syncthreads();
    }
    if ((int)threadIdx.x < nb) bsums[threadIdx.x] = s[threadIdx.x] - v;
}

__global__ void scan3d_kernel(int* __restrict__ ptr, const int* __restrict__ bsums,
                              const int* __restrict__ cnt, float* __restrict__ dis,
                              int n, int E) {
    int i = blockIdx.x * 1024 + threadIdx.x;
    if (i < n) {
        ptr[i] += bsums[blockIdx.x];
        dis[i] = rsqrtf((float)(cnt[i] + 1));
    }
    if (i == 0) ptr[n] = E;
}

// fill CSR with (src_row, norm=dis[r]*dis[c]) pairs
__global__ void fill_kernel(const int* __restrict__ row, const int* __restrict__ col,
                            const int* __restrict__ ptr, int* __restrict__ fillc,
                            const float* __restrict__ dis, uint2* __restrict__ csr_en, int E) {
    int e = blockIdx.x * 256 + threadIdx.x;
    if (e < E) {
        int c = col[e];
        int r = row[e];
        int p = ptr[c] + atomicAdd(&fillc[c], 1);
        uint2 en;
        en.x = (unsigned int)r;
        en.y = __float_as_uint(dis[r] * dis[c]);
        csr_en[p] = en;
    }
}

// ---------------- gemm1: 512->64, LDS-staged coalesced (identical to R9) ----
__global__ __launch_bounds__(256) void gemm1_kernel(const float* __restrict__ Ap,
                                                    const unsigned short* __restrict__ Wf,
                                                    unsigned short* __restrict__ Y, int N) {
    __shared__ unsigned short As[2][64][136];
    const int t = threadIdx.x;
    const int lane = t & 63;
    const int wid = t >> 6;
    const int rbase = blockIdx.x * 64;
    const int fr = lane & 15;
    const int khalf = lane >> 4;

    f32x4 acc[4];
#pragma unroll
    for (int nt = 0; nt < 4; nt++)
#pragma unroll
        for (int j = 0; j < 4; j++) acc[nt][j] = 0.f;

    auto stage = [&](int buf, int c) {
#pragma unroll
        for (int rd = 0; rd < 8; rd++) {
            int u = t + rd * 256;
            int row = u >> 5;           // 0..63
            int q = u & 31;             // float4 index within 128-float chunk
            int gr = rbase + row; if (gr > N - 1) gr = N - 1;
            float4 v = *(const float4*)(Ap + (size_t)gr * 512 + c * 128 + q * 4);
            uint2 w;
            w.x = (unsigned int)f2bf(v.x) | ((unsigned int)f2bf(v.y) << 16);
            w.y = (unsigned int)f2bf(v.z) | ((unsigned int)f2bf(v.w) << 16);
            *(uint2*)&As[buf][row][q * 4] = w;
        }
    };

    stage(0, 0);
    __syncthreads();
#pragma unroll
    for (int c = 0; c < 4; c++) {
        if (c < 3) stage((c + 1) & 1, c + 1);
#pragma unroll
        for (int ks = 0; ks < 4; ks++) {
            short8 afr = *(const short8*)&As[c & 1][wid * 16 + fr][ks * 32 + khalf * 8];
            const int ksg = c * 4 + ks;
#pragma unroll
            for (int nt = 0; nt < 4; nt++) {
                short8 bfr = *(const short8*)(Wf + (((size_t)nt * 16 + ksg) * 64 + lane) * 8);
                acc[nt] = __builtin_amdgcn_mfma_f32_16x16x32_bf16(afr, bfr, acc[nt], 0, 0, 0);
            }
        }
        __syncthreads();
    }

    const int rD0 = rbase + wid * 16 + (lane >> 4) * 4;
    const int colb = lane & 15;
#pragma unroll
    for (int nt = 0; nt < 4; nt++) {
        int c = nt * 16 + colb;
#pragma unroll
        for (int i = 0; i < 4; i++) {
            int rD = rD0 + i;
            if (rD < N) Y[(size_t)rD * 64 + c] = f2bf(acc[nt][i]);
        }
    }
}

// ---------------- fused gemm2 (64->128, +b2, relu) -> LDS -> gemm3 (128->40) -
__global__ __launch_bounds__(256) void gemm23_kernel(const unsigned short* __restrict__ A,
                                                     const unsigned short* __restrict__ Wf2,
                                                     const float* __restrict__ b2,
                                                     const unsigned short* __restrict__ Wf3,
                                                     unsigned short* __restrict__ Y, int N) {
    __shared__ unsigned short hs[4][16][136];   // +8 pad: 272B stride, 2-way banks (free)
    const int lane = threadIdx.x & 63;
    const int wid = threadIdx.x >> 6;
    const int rbase = blockIdx.x * 64 + wid * 16;
    const int rA = rbase + (lane & 15);
    const bool va = rA < N;
    const int khalf = lane >> 4;

    f32x4 acc2[8];
#pragma unroll
    for (int nt = 0; nt < 8; nt++)
#pragma unroll
        for (int j = 0; j < 4; j++) acc2[nt][j] = 0.f;

#pragma unroll
    for (int ks = 0; ks < 2; ks++) {
        short8 afr;
        if (va) afr = *(const short8*)(A + (size_t)rA * 64 + ks * 32 + khalf * 8);
        else {
#pragma unroll
            for (int j = 0; j < 8; j++) afr[j] = 0;
        }
#pragma unroll
        for (int nt = 0; nt < 8; nt++) {
            short8 bfr = *(const short8*)(Wf2 + (((size_t)nt * 2 + ks) * 64 + lane) * 8);
            acc2[nt] = __builtin_amdgcn_mfma_f32_16x16x32_bf16(afr, bfr, acc2[nt], 0, 0, 0);
        }
    }

    const int rD = (lane >> 4) * 4;
    const int colb = lane & 15;
#pragma unroll
    for (int nt = 0; nt < 8; nt++) {
        int c = nt * 16 + colb;
        float bv = b2[c];
#pragma unroll
        for (int j = 0; j < 4; j++)
            hs[wid][rD + j][c] = f2bf(fmaxf(acc2[nt][j] + bv, 0.f));
    }
    __syncthreads();

    f32x4 acc3[3];
#pragma unroll
    for (int nt = 0; nt < 3; nt++)
#pragma unroll
        for (int j = 0; j < 4; j++) acc3[nt][j] = 0.f;

    const int r = lane & 15;
#pragma unroll
    for (int ks = 0; ks < 4; ks++) {
        short8 afr = *(const short8*)&hs[wid][r][ks * 32 + khalf * 8];
#pragma unroll
        for (int nt = 0; nt < 3; nt++) {
            short8 bfr = *(const short8*)(Wf3 + (((size_t)nt * 4 + ks) * 64 + lane) * 8);
            acc3[nt] = __builtin_amdgcn_mfma_f32_16x16x32_bf16(afr, bfr, acc3[nt], 0, 0, 0);
        }
    }

#pragma unroll
    for (int nt = 0; nt < 3; nt++) {
        int c = nt * 16 + colb;
        if (c < 40) {
#pragma unroll
            for (int i = 0; i < 4; i++) {
                int rr = rbase + rD + i;
                if (rr < N) Y[(size_t)rr * 40 + c] = f2bf(acc3[nt][i]);
            }
        }
    }
}

// ---------------- F=64 aggregation: 8 slots x 8 lanes ----------------
template <bool BR>
__global__ __launch_bounds__(256) void agg64_kernel(const unsigned int* __restrict__ XW,
                                                    const float* __restrict__ bias,
                                                    const int* __restrict__ ptr,
                                                    const uint2* __restrict__ EN,
                                                    unsigned int* __restrict__ Y, int N) {
    const int lane = threadIdx.x & 63;
    const int wid = threadIdx.x >> 6;
    const int n = blockIdx.x * 4 + wid;
    if (n >= N) return;
    const int s = lane >> 3;        // edge slot 0..7
    const int q = lane & 7;         // uint4 index within row

    const int e0 = ptr[n], e1 = ptr[n + 1];
    const float selfw = 1.0f / (float)(e1 - e0 + 1);   // dis[n]^2

    float acc[8];
    if (s == 0) {
        const uint4 u = *(const uint4*)(XW + (size_t)n * 32 + q * 4);
        acc[0] = selfw * bflo(u.x); acc[1] = selfw * bfhi(u.x);
        acc[2] = selfw * bflo(u.y); acc[3] = selfw * bfhi(u.y);
        acc[4] = selfw * bflo(u.z); acc[5] = selfw * bfhi(u.z);
        acc[6] = selfw * bflo(u.w); acc[7] = selfw * bfhi(u.w);
    } else {
#pragma unroll
        for (int j = 0; j < 8; j++) acc[j] = 0.f;
    }

    for (int eb = e0; eb < e1; eb += 64) {
        int cnt = e1 - eb; if (cnt > 64) cnt = 64;
        uint2 en;
        if (lane < cnt) en = EN[eb + lane];
        else { en.x = 0; en.y = 0; }
#pragma unroll 2
        for (int k = s; k < cnt; k += 8) {
            int r = __shfl((int)en.x, k);
            float nrm = __uint_as_float((unsigned int)__shfl((int)en.y, k));
            const uint4 u = *(const uint4*)(XW + (size_t)r * 32 + q * 4);
            acc[0] += nrm * bflo(u.x); acc[1] += nrm * bfhi(u.x);
            acc[2] += nrm * bflo(u.y); acc[3] += nrm * bfhi(u.y);
            acc[4] += nrm * bflo(u.z); acc[5] += nrm * bfhi(u.z);
            acc[6] += nrm * bflo(u.w); acc[7] += nrm * bfhi(u.w);
        }
    }

#pragma unroll
    for (int off = 8; off < 64; off <<= 1)
#pragma unroll
        for (int j = 0; j < 8; j++) acc[j] += __shfl_xor(acc[j], off);

    if (lane < 8) {
        float v[8];
        if (BR) {
            const float4 b0 = *((const float4*)bias + lane * 2);
            const float4 b1 = *((const float4*)bias + lane * 2 + 1);
            v[0] = fmaxf(acc[0] + b0.x, 0.f); v[1] = fmaxf(acc[1] + b0.y, 0.f);
            v[2] = fmaxf(acc[2] + b0.z, 0.f); v[3] = fmaxf(acc[3] + b0.w, 0.f);
            v[4] = fmaxf(acc[4] + b1.x, 0.f); v[5] = fmaxf(acc[5] + b1.y, 0.f);
            v[6] = fmaxf(acc[6] + b1.z, 0.f); v[7] = fmaxf(acc[7] + b1.w, 0.f);
        } else {
#pragma unroll
            for (int j = 0; j < 8; j++) v[j] = acc[j];
        }
        uint4 o;
        o.x = (unsigned int)f2bf(v[0]) | ((unsigned int)f2bf(v[1]) << 16);
        o.y = (unsigned int)f2bf(v[2]) | ((unsigned int)f2bf(v[3]) << 16);
        o.z = (unsigned int)f2bf(v[4]) | ((unsigned int)f2bf(v[5]) << 16);
        o.w = (unsigned int)f2bf(v[6]) | ((unsigned int)f2bf(v[7]) << 16);
        *(uint4*)(Y + (size_t)n * 32 + lane * 4) = o;
    }
}

// ---------------- F=40 agg + bias + log_softmax: 4 slots x 16 lanes ---------
__global__ __launch_bounds__(256) void agg40lsm_kernel(const unsigned int* __restrict__ XW,
                                                       const float* __restrict__ bias,
                                                       const int* __restrict__ ptr,
                                                       const uint2* __restrict__ EN,
                                                       float* __restrict__ out, int N) {
    const int lane = threadIdx.x & 63;
    const int wid = threadIdx.x >> 6;
    const int n = blockIdx.x * 4 + wid;
    if (n >= N) return;
    const int s = lane >> 4;        // edge slot 0..3
    const int c = lane & 15;        // uint2 index, active c<10
    const bool act = (c < 10);

    const int e0 = ptr[n], e1 = ptr[n + 1];
    const float selfw = 1.0f / (float)(e1 - e0 + 1);

    float acc[4] = {0.f, 0.f, 0.f, 0.f};
    if (s == 0 && act) {
        const uint2 u = *(const uint2*)(XW + (size_t)n * 20 + c * 2);
        acc[0] = selfw * bflo(u.x); acc[1] = selfw * bfhi(u.x);
        acc[2] = selfw * bflo(u.y); acc[3] = selfw * bfhi(u.y);
    }

    for (int eb = e0; eb < e1; eb += 64) {
        int cnt = e1 - eb; if (cnt > 64) cnt = 64;
        uint2 en;
        if (lane < cnt) en = EN[eb + lane];
        else { en.x = 0; en.y = 0; }
#pragma unroll 2
        for (int k = s; k < cnt; k += 4) {
            int r = __shfl((int)en.x, k);
            float nrm = __uint_as_float((unsigned int)__shfl((int)en.y, k));
            if (act) {
                const uint2 u = *(const uint2*)(XW + (size_t)r * 20 + c * 2);
                acc[0] += nrm * bflo(u.x); acc[1] += nrm * bfhi(u.x);
                acc[2] += nrm * bflo(u.y); acc[3] += nrm * bfhi(u.y);
            }
        }
    }

#pragma unroll
    for (int off = 16; off < 64; off <<= 1)
#pragma unroll
        for (int j = 0; j < 4; j++) acc[j] += __shfl_xor(acc[j], off);

    float v[4];
    float m = -INFINITY;
    if (lane < 16 && act) {
        const float4 b = *((const float4*)bias + c);
        v[0] = acc[0] + b.x; v[1] = acc[1] + b.y;
        v[2] = acc[2] + b.z; v[3] = acc[3] + b.w;
        m = fmaxf(fmaxf(v[0], v[1]), fmaxf(v[2], v[3]));
    }
#pragma unroll
    for (int off = 32; off; off >>= 1) m = fmaxf(m, __shfl_xor(m, off));
    float ex = 0.f;
    if (lane < 16 && act)
        ex = expf(v[0] - m) + expf(v[1] - m) + expf(v[2] - m) + expf(v[3] - m);
#pragma unroll
    for (int off = 32; off; off >>= 1) ex += __shfl_xor(ex, off);
    float ls = logf(ex);
    if (lane < 16 && act) {
        float4 o;
        o.x = v[0] - m - ls; o.y = v[1] - m - ls;
        o.z = v[2] - m - ls; o.w = v[3] - m - ls;
        *(float4*)(out + (size_t)n * 40 + c * 4) = o;
    }
}

// ---------------- launch ----------------

extern "C" void kernel_launch(void* const* d_in, const int* in_sizes, int n_in,
                              void* d_out, int out_size, void* d_ws, size_t ws_size,
                              hipStream_t stream) {
    const float* x  = (const float*)d_in[0];
    const int*   ei = (const int*)d_in[1];
    const float* W1 = (const float*)d_in[2];
    const float* b1 = (const float*)d_in[3];
    const float* W2 = (const float*)d_in[4];
    const float* b2 = (const float*)d_in[5];
    const float* W3 = (const float*)d_in[6];
    const float* b3 = (const float*)d_in[7];
    const int N = in_sizes[0] / 512;
    const int E = in_sizes[1] / 2;
    const int* row = ei;
    const int* col = ei + E;

    char* p = (char*)d_ws;
    auto alloc = [&](size_t bytes) {
        void* r = (void*)p;
        p += (bytes + 255) & ~(size_t)255;
        return r;
    };
    float* dis    = (float*)alloc((size_t)N * 4);
    int*   cnt    = (int*)alloc((size_t)N * 4);
    int*   ptr    = (int*)alloc((size_t)(N + 1) * 4);
    int*   fillc  = (int*)alloc((size_t)N * 4);
    int*   bsums  = (int*)alloc(1024);
    uint2* csr_en = (uint2*)alloc((size_t)E * 8);
    unsigned short* Wf1 = (unsigned short*)alloc(4 * 16 * 64 * 8 * 2);
    unsigned short* Wf2 = (unsigned short*)alloc(8 * 2 * 64 * 8 * 2);
    unsigned short* Wf3 = (unsigned short*)alloc(3 * 4 * 64 * 8 * 2);
    unsigned short* xw1 = (unsigned short*)alloc((size_t)N * 64 * 2);
    unsigned short* xw1b= (unsigned short*)alloc((size_t)N * 64 * 2);   // measurement scratch
    unsigned short* xw1c= (unsigned short*)alloc((size_t)N * 64 * 2);   // measurement scratch
    unsigned short* h1  = (unsigned short*)alloc((size_t)N * 64 * 2);
    unsigned short* a2  = (unsigned short*)alloc((size_t)N * 64 * 2);
    unsigned short* xw3 = (unsigned short*)alloc((size_t)N * 40 * 2);
    float* out = (float*)d_out;

    // prep: W fragments + zero cnt/fillc
    prep_kernel<<<(2 * N + 255) / 256, 256, 0, stream>>>(W1, W2, W3, Wf1, Wf2, Wf3,
                                                         cnt, fillc, N);

    const int cgrid = (E + 255) / 256;
    count_kernel<<<cgrid, 256, 0, stream>>>(col, cnt, E);

    // gemm1 x3: two scratch copies for in-band timing, one real.
    // G = (dur_R10 - dur_R9) / 2.
    const int ggrid = (N + 63) / 64;
    gemm1_kernel<<<ggrid, 256, 0, stream>>>(x, Wf1, xw1b, N);
    gemm1_kernel<<<ggrid, 256, 0, stream>>>(x, Wf1, xw1c, N);
    gemm1_kernel<<<ggrid, 256, 0, stream>>>(x, Wf1, xw1, N);

    // scan + dis + fill
    int nb = (N + 1023) / 1024;
    scan1_kernel<<<nb, 1024, 0, stream>>>(cnt, ptr, bsums, N);
    scan2_kernel<<<1, 128, 0, stream>>>(bsums, nb);
    scan3d_kernel<<<nb, 1024, 0, stream>>>(ptr, bsums, cnt, dis, N, E);
    fill_kernel<<<cgrid, 256, 0, stream>>>(row, col, ptr, fillc, dis, csr_en, E);

    const int ngrid = (N + 3) / 4;

    // h1 = relu(Ahat xw1 + b1)
    agg64_kernel<true><<<ngrid, 256, 0, stream>>>((const unsigned int*)xw1, b1, ptr, csr_en,
                                                  (unsigned int*)h1, N);
    // a2 = Ahat h1 ; xw3 = relu(a2 W2 + b2) W3
    agg64_kernel<false><<<ngrid, 256, 0, stream>>>((const unsigned int*)h1, nullptr, ptr, csr_en,
                                                   (unsigned int*)a2, N);
    gemm23_kernel<<<ggrid, 256, 0, stream>>>(a2, Wf2, b2, Wf3, xw3, N);
    // out = log_softmax(Ahat xw3 + b3)
    agg40lsm_kernel<<<ngrid, 256, 0, stream>>>((const unsigned int*)xw3, b3, ptr, csr_en, out, N);
}

// Round 11
// 330.900 us; speedup vs baseline: 1.3369x; 1.3369x over previous
//
#include <hip/hip_runtime.h>
#include <math.h>

// ---------------------------------------------------------------------------
// 3-layer GCN on MI355X.
//   h1 = relu(Ahat @ (x W1) + b1)          gather at F=64
//   h2 = relu((Ahat @ h1) W2 + b2)         reordered: gather at F=64, not 128
//   out = log_softmax(Ahat @ (h2 W3) + b3) gather at F=40
// R11: (a) gemm1 measured at ~39us (R10) = near HBM floor -> leave alone.
// (b) agg64 processes TWO nodes per wave (16 independent row-gathers in
// flight, reduce depth unchanged). (c) fill made atomic-free: count pass
// stores slot[e]=atomicAdd(...), fill is pure streaming.
// ---------------------------------------------------------------------------

typedef __attribute__((ext_vector_type(8))) short short8;
typedef __attribute__((ext_vector_type(4))) float f32x4;

__device__ __forceinline__ unsigned short f2bf(float f) {
    unsigned int u = __float_as_uint(f);
    unsigned int r = (u + 0x7fffu + ((u >> 16) & 1u)) >> 16;   // RNE
    return (unsigned short)r;
}
__device__ __forceinline__ float bflo(unsigned int u) { return __uint_as_float(u << 16); }
__device__ __forceinline__ float bfhi(unsigned int u) { return __uint_as_float(u & 0xffff0000u); }

// ---------------- prep: W fragment pack + zero cnt ----------------
__device__ __forceinline__ void wprep_one(const float* W, unsigned short* out,
                                          int KS, int FOUT, int t) {
    int i = t & 7;
    int l = (t >> 3) & 63;
    int g = t >> 9;
    int ks = g % KS;
    int nt = g / KS;
    int k = ks * 32 + (l >> 4) * 8 + i;
    int c = nt * 16 + (l & 15);
    out[t] = (c < FOUT) ? f2bf(W[(size_t)k * FOUT + c]) : (unsigned short)0;
}

__global__ void prep_kernel(const float* __restrict__ W1, const float* __restrict__ W2,
                            const float* __restrict__ W3,
                            unsigned short* __restrict__ Wf1, unsigned short* __restrict__ Wf2,
                            unsigned short* __restrict__ Wf3,
                            int* __restrict__ cnt, int N) {
    int t = blockIdx.x * 256 + threadIdx.x;
    if (t < 32768)       wprep_one(W1, Wf1, 16, 64, t);
    else if (t < 40960)  wprep_one(W2, Wf2, 2, 128, t - 32768);
    else if (t < 47104)  wprep_one(W3, Wf3, 4, 40, t - 40960);
    if (t < N) cnt[t] = 0;
}

// count + record per-edge slot (atomic paid once; fill becomes streaming)
__global__ void countslot_kernel(const int* __restrict__ col, int* __restrict__ cnt,
                                 int* __restrict__ slot, int E) {
    int e = blockIdx.x * 256 + threadIdx.x;
    if (e < E) slot[e] = atomicAdd(&cnt[col[e]], 1);
}

// ---------------- scan ----------------
__global__ void scan1_kernel(const int* __restrict__ cnt, int* __restrict__ out,
                             int* __restrict__ bsums, int n) {
    __shared__ int s[1024];
    int i = blockIdx.x * 1024 + threadIdx.x;
    int v = (i < n) ? cnt[i] : 0;
    s[threadIdx.x] = v;
    __syncthreads();
    for (int off = 1; off < 1024; off <<= 1) {
        int t = 0;
        if ((int)threadIdx.x >= off) t = s[threadIdx.x - off];
        __syncthreads();
        if ((int)threadIdx.x >= off) s[threadIdx.x] += t;
        __syncthreads();
    }
    if (i < n) out[i] = s[threadIdx.x] - v;
    if (threadIdx.x == 1023) bsums[blockIdx.x] = s[1023];
}

__global__ void scan2_kernel(int* bsums, int nb) {
    __shared__ int s[128];
    int v = ((int)threadIdx.x < nb) ? bsums[threadIdx.x] : 0;
    s[threadIdx.x] = v;
    __syncthreads();
    for (int off = 1; off < 128; off <<= 1) {
        int t = 0;
        if ((int)threadIdx.x >= off) t = s[threadIdx.x - off];
        __syncthreads();
        if ((int)threadIdx.x >= off) s[threadIdx.x] += t;
        __syncthreads();
    }
    if ((int)threadIdx.x < nb) bsums[threadIdx.x] = s[threadIdx.x] - v;
}

__global__ void scan3d_kernel(int* __restrict__ ptr, const int* __restrict__ bsums,
                              const int* __restrict__ cnt, float* __restrict__ dis,
                              int n, int E) {
    int i = blockIdx.x * 1024 + threadIdx.x;
    if (i < n) {
        ptr[i] += bsums[blockIdx.x];
        dis[i] = rsqrtf((float)(cnt[i] + 1));
    }
    if (i == 0) ptr[n] = E;
}

// fill CSR with (src_row, norm) pairs — NO atomics (slot precomputed)
__global__ void fill_kernel(const int* __restrict__ row, const int* __restrict__ col,
                            const int* __restrict__ ptr, const int* __restrict__ slot,
                            const float* __restrict__ dis, uint2* __restrict__ csr_en, int E) {
    int e = blockIdx.x * 256 + threadIdx.x;
    if (e < E) {
        int c = col[e];
        int r = row[e];
        int p = ptr[c] + slot[e];
        uint2 en;
        en.x = (unsigned int)r;
        en.y = __float_as_uint(dis[r] * dis[c]);
        csr_en[p] = en;
    }
}

// ---------------- gemm1: 512->64, LDS-staged coalesced (R9, measured ~39us) -
__global__ __launch_bounds__(256) void gemm1_kernel(const float* __restrict__ Ap,
                                                    const unsigned short* __restrict__ Wf,
                                                    unsigned short* __restrict__ Y, int N) {
    __shared__ unsigned short As[2][64][136];
    const int t = threadIdx.x;
    const int lane = t & 63;
    const int wid = t >> 6;
    const int rbase = blockIdx.x * 64;
    const int fr = lane & 15;
    const int khalf = lane >> 4;

    f32x4 acc[4];
#pragma unroll
    for (int nt = 0; nt < 4; nt++)
#pragma unroll
        for (int j = 0; j < 4; j++) acc[nt][j] = 0.f;

    auto stage = [&](int buf, int c) {
#pragma unroll
        for (int rd = 0; rd < 8; rd++) {
            int u = t + rd * 256;
            int row = u >> 5;
            int q = u & 31;
            int gr = rbase + row; if (gr > N - 1) gr = N - 1;
            float4 v = *(const float4*)(Ap + (size_t)gr * 512 + c * 128 + q * 4);
            uint2 w;
            w.x = (unsigned int)f2bf(v.x) | ((unsigned int)f2bf(v.y) << 16);
            w.y = (unsigned int)f2bf(v.z) | ((unsigned int)f2bf(v.w) << 16);
            *(uint2*)&As[buf][row][q * 4] = w;
        }
    };

    stage(0, 0);
    __syncthreads();
#pragma unroll
    for (int c = 0; c < 4; c++) {
        if (c < 3) stage((c + 1) & 1, c + 1);
#pragma unroll
        for (int ks = 0; ks < 4; ks++) {
            short8 afr = *(const short8*)&As[c & 1][wid * 16 + fr][ks * 32 + khalf * 8];
            const int ksg = c * 4 + ks;
#pragma unroll
            for (int nt = 0; nt < 4; nt++) {
                short8 bfr = *(const short8*)(Wf + (((size_t)nt * 16 + ksg) * 64 + lane) * 8);
                acc[nt] = __builtin_amdgcn_mfma_f32_16x16x32_bf16(afr, bfr, acc[nt], 0, 0, 0);
            }
        }
        __syncthreads();
    }

    const int rD0 = rbase + wid * 16 + (lane >> 4) * 4;
    const int colb = lane & 15;
#pragma unroll
    for (int nt = 0; nt < 4; nt++) {
        int c = nt * 16 + colb;
#pragma unroll
        for (int i = 0; i < 4; i++) {
            int rD = rD0 + i;
            if (rD < N) Y[(size_t)rD * 64 + c] = f2bf(acc[nt][i]);
        }
    }
}

// ---------------- fused gemm2 (64->128, +b2, relu) -> LDS -> gemm3 (128->40) -
__global__ __launch_bounds__(256) void gemm23_kernel(const unsigned short* __restrict__ A,
                                                     const unsigned short* __restrict__ Wf2,
                                                     const float* __restrict__ b2,
                                                     const unsigned short* __restrict__ Wf3,
                                                     unsigned short* __restrict__ Y, int N) {
    __shared__ unsigned short hs[4][16][136];
    const int lane = threadIdx.x & 63;
    const int wid = threadIdx.x >> 6;
    const int rbase = blockIdx.x * 64 + wid * 16;
    const int rA = rbase + (lane & 15);
    const bool va = rA < N;
    const int khalf = lane >> 4;

    f32x4 acc2[8];
#pragma unroll
    for (int nt = 0; nt < 8; nt++)
#pragma unroll
        for (int j = 0; j < 4; j++) acc2[nt][j] = 0.f;

#pragma unroll
    for (int ks = 0; ks < 2; ks++) {
        short8 afr;
        if (va) afr = *(const short8*)(A + (size_t)rA * 64 + ks * 32 + khalf * 8);
        else {
#pragma unroll
            for (int j = 0; j < 8; j++) afr[j] = 0;
        }
#pragma unroll
        for (int nt = 0; nt < 8; nt++) {
            short8 bfr = *(const short8*)(Wf2 + (((size_t)nt * 2 + ks) * 64 + lane) * 8);
            acc2[nt] = __builtin_amdgcn_mfma_f32_16x16x32_bf16(afr, bfr, acc2[nt], 0, 0, 0);
        }
    }

    const int rD = (lane >> 4) * 4;
    const int colb = lane & 15;
#pragma unroll
    for (int nt = 0; nt < 8; nt++) {
        int c = nt * 16 + colb;
        float bv = b2[c];
#pragma unroll
        for (int j = 0; j < 4; j++)
            hs[wid][rD + j][c] = f2bf(fmaxf(acc2[nt][j] + bv, 0.f));
    }
    __syncthreads();

    f32x4 acc3[3];
#pragma unroll
    for (int nt = 0; nt < 3; nt++)
#pragma unroll
        for (int j = 0; j < 4; j++) acc3[nt][j] = 0.f;

    const int r = lane & 15;
#pragma unroll
    for (int ks = 0; ks < 4; ks++) {
        short8 afr = *(const short8*)&hs[wid][r][ks * 32 + khalf * 8];
#pragma unroll
        for (int nt = 0; nt < 3; nt++) {
            short8 bfr = *(const short8*)(Wf3 + (((size_t)nt * 4 + ks) * 64 + lane) * 8);
            acc3[nt] = __builtin_amdgcn_mfma_f32_16x16x32_bf16(afr, bfr, acc3[nt], 0, 0, 0);
        }
    }

#pragma unroll
    for (int nt = 0; nt < 3; nt++) {
        int c = nt * 16 + colb;
        if (c < 40) {
#pragma unroll
            for (int i = 0; i < 4; i++) {
                int rr = rbase + rD + i;
                if (rr < N) Y[(size_t)rr * 40 + c] = f2bf(acc3[nt][i]);
            }
        }
    }
}

// ---------------- F=64 aggregation: TWO nodes per wave, 8 slots x 8 lanes ---
// Per wave: nodes nA=2w, nB=2w+1. Both gather chains interleave -> up to 16
// independent row-loads in flight; xor-reduce depth unchanged (3 stages).
template <bool BR>
__global__ __launch_bounds__(256) void agg64_kernel(const unsigned int* __restrict__ XW,
                                                    const float* __restrict__ bias,
                                                    const int* __restrict__ ptr,
                                                    const uint2* __restrict__ EN,
                                                    unsigned int* __restrict__ Y, int N) {
    const int lane = threadIdx.x & 63;
    const int wid = threadIdx.x >> 6;
    const int nA = (blockIdx.x * 4 + wid) * 2;
    const int nB = nA + 1;
    if (nA >= N) return;
    const bool hasB = (nB < N);
    const int s = lane >> 3;        // edge slot 0..7
    const int q = lane & 7;         // uint4 index within row

    const int e0A = ptr[nA], e1A = ptr[nA + 1];
    const int e0B = hasB ? ptr[nB] : 0;
    const int e1B = hasB ? ptr[nB + 1] : 0;
    const float selfwA = 1.0f / (float)(e1A - e0A + 1);
    const float selfwB = hasB ? 1.0f / (float)(e1B - e0B + 1) : 0.f;

    float accA[8], accB[8];
#pragma unroll
    for (int j = 0; j < 8; j++) { accA[j] = 0.f; accB[j] = 0.f; }
    if (s == 0) {
        const uint4 uA = *(const uint4*)(XW + (size_t)nA * 32 + q * 4);
        accA[0] = selfwA * bflo(uA.x); accA[1] = selfwA * bfhi(uA.x);
        accA[2] = selfwA * bflo(uA.y); accA[3] = selfwA * bfhi(uA.y);
        accA[4] = selfwA * bflo(uA.z); accA[5] = selfwA * bfhi(uA.z);
        accA[6] = selfwA * bflo(uA.w); accA[7] = selfwA * bfhi(uA.w);
        if (hasB) {
            const uint4 uB = *(const uint4*)(XW + (size_t)nB * 32 + q * 4);
            accB[0] = selfwB * bflo(uB.x); accB[1] = selfwB * bfhi(uB.x);
            accB[2] = selfwB * bflo(uB.y); accB[3] = selfwB * bfhi(uB.y);
            accB[4] = selfwB * bflo(uB.z); accB[5] = selfwB * bfhi(uB.z);
            accB[6] = selfwB * bflo(uB.w); accB[7] = selfwB * bfhi(uB.w);
        }
    }

    for (int ebA = e0A, ebB = e0B; ebA < e1A || ebB < e1B; ebA += 64, ebB += 64) {
        int cntA = e1A - ebA; if (cntA > 64) cntA = 64; if (cntA < 0) cntA = 0;
        int cntB = e1B - ebB; if (cntB > 64) cntB = 64; if (cntB < 0) cntB = 0;
        uint2 enA, enB;
        if (lane < cntA) enA = EN[ebA + lane]; else { enA.x = 0; enA.y = 0; }
        if (lane < cntB) enB = EN[ebB + lane]; else { enB.x = 0; enB.y = 0; }
        int kmax = cntA > cntB ? cntA : cntB;
        for (int k = s; k < kmax; k += 8) {
            if (k < cntA) {
                int r = __shfl((int)enA.x, k);
                float nrm = __uint_as_float((unsigned int)__shfl((int)enA.y, k));
                const uint4 u = *(const uint4*)(XW + (size_t)r * 32 + q * 4);
                accA[0] += nrm * bflo(u.x); accA[1] += nrm * bfhi(u.x);
                accA[2] += nrm * bflo(u.y); accA[3] += nrm * bfhi(u.y);
                accA[4] += nrm * bflo(u.z); accA[5] += nrm * bfhi(u.z);
                accA[6] += nrm * bflo(u.w); accA[7] += nrm * bfhi(u.w);
            }
            if (k < cntB) {
                int r = __shfl((int)enB.x, k);
                float nrm = __uint_as_float((unsigned int)__shfl((int)enB.y, k));
                const uint4 u = *(const uint4*)(XW + (size_t)r * 32 + q * 4);
                accB[0] += nrm * bflo(u.x); accB[1] += nrm * bfhi(u.x);
                accB[2] += nrm * bflo(u.y); accB[3] += nrm * bfhi(u.y);
                accB[4] += nrm * bflo(u.z); accB[5] += nrm * bfhi(u.z);
                accB[6] += nrm * bflo(u.w); accB[7] += nrm * bfhi(u.w);
            }
        }
    }

#pragma unroll
    for (int off = 8; off < 64; off <<= 1)
#pragma unroll
        for (int j = 0; j < 8; j++) {
            accA[j] += __shfl_xor(accA[j], off);
            accB[j] += __shfl_xor(accB[j], off);
        }

    if (lane < 8) {
        float vA[8], vB[8];
        if (BR) {
            const float4 b0 = *((const float4*)bias + lane * 2);
            const float4 b1 = *((const float4*)bias + lane * 2 + 1);
            vA[0] = fmaxf(accA[0] + b0.x, 0.f); vA[1] = fmaxf(accA[1] + b0.y, 0.f);
            vA[2] = fmaxf(accA[2] + b0.z, 0.f); vA[3] = fmaxf(accA[3] + b0.w, 0.f);
            vA[4] = fmaxf(accA[4] + b1.x, 0.f); vA[5] = fmaxf(accA[5] + b1.y, 0.f);
            vA[6] = fmaxf(accA[6] + b1.z, 0.f); vA[7] = fmaxf(accA[7] + b1.w, 0.f);
            vB[0] = fmaxf(accB[0] + b0.x, 0.f); vB[1] = fmaxf(accB[1] + b0.y, 0.f);
            vB[2] = fmaxf(accB[2] + b0.z, 0.f); vB[3] = fmaxf(accB[3] + b0.w, 0.f);
            vB[4] = fmaxf(accB[4] + b1.x, 0.f); vB[5] = fmaxf(accB[5] + b1.y, 0.f);
            vB[6] = fmaxf(accB[6] + b1.z, 0.f); vB[7] = fmaxf(accB[7] + b1.w, 0.f);
        } else {
#pragma unroll
            for (int j = 0; j < 8; j++) { vA[j] = accA[j]; vB[j] = accB[j]; }
        }
        uint4 oA, oB;
        oA.x = (unsigned int)f2bf(vA[0]) | ((unsigned int)f2bf(vA[1]) << 16);
        oA.y = (unsigned int)f2bf(vA[2]) | ((unsigned int)f2bf(vA[3]) << 16);
        oA.z = (unsigned int)f2bf(vA[4]) | ((unsigned int)f2bf(vA[5]) << 16);
        oA.w = (unsigned int)f2bf(vA[6]) | ((unsigned int)f2bf(vA[7]) << 16);
        *(uint4*)(Y + (size_t)nA * 32 + lane * 4) = oA;
        if (hasB) {
            oB.x = (unsigned int)f2bf(vB[0]) | ((unsigned int)f2bf(vB[1]) << 16);
            oB.y = (unsigned int)f2bf(vB[2]) | ((unsigned int)f2bf(vB[3]) << 16);
            oB.z = (unsigned int)f2bf(vB[4]) | ((unsigned int)f2bf(vB[5]) << 16);
            oB.w = (unsigned int)f2bf(vB[6]) | ((unsigned int)f2bf(vB[7]) << 16);
            *(uint4*)(Y + (size_t)nB * 32 + lane * 4) = oB;
        }
    }
}

// ---------------- F=40 agg + bias + log_softmax: 4 slots x 16 lanes ---------
__global__ __launch_bounds__(256) void agg40lsm_kernel(const unsigned int* __restrict__ XW,
                                                       const float* __restrict__ bias,
                                                       const int* __restrict__ ptr,
                                                       const uint2* __restrict__ EN,
                                                       float* __restrict__ out, int N) {
    const int lane = threadIdx.x & 63;
    const int wid = threadIdx.x >> 6;
    const int n = blockIdx.x * 4 + wid;
    if (n >= N) return;
    const int s = lane >> 4;        // edge slot 0..3
    const int c = lane & 15;        // uint2 index, active c<10
    const bool act = (c < 10);

    const int e0 = ptr[n], e1 = ptr[n + 1];
    const float selfw = 1.0f / (float)(e1 - e0 + 1);

    float acc[4] = {0.f, 0.f, 0.f, 0.f};
    if (s == 0 && act) {
        const uint2 u = *(const uint2*)(XW + (size_t)n * 20 + c * 2);
        acc[0] = selfw * bflo(u.x); acc[1] = selfw * bfhi(u.x);
        acc[2] = selfw * bflo(u.y); acc[3] = selfw * bfhi(u.y);
    }

    for (int eb = e0; eb < e1; eb += 64) {
        int cnt = e1 - eb; if (cnt > 64) cnt = 64;
        uint2 en;
        if (lane < cnt) en = EN[eb + lane];
        else { en.x = 0; en.y = 0; }
#pragma unroll 2
        for (int k = s; k < cnt; k += 4) {
            int r = __shfl((int)en.x, k);
            float nrm = __uint_as_float((unsigned int)__shfl((int)en.y, k));
            if (act) {
                const uint2 u = *(const uint2*)(XW + (size_t)r * 20 + c * 2);
                acc[0] += nrm * bflo(u.x); acc[1] += nrm * bfhi(u.x);
                acc[2] += nrm * bflo(u.y); acc[3] += nrm * bfhi(u.y);
            }
        }
    }

#pragma unroll
    for (int off = 16; off < 64; off <<= 1)
#pragma unroll
        for (int j = 0; j < 4; j++) acc[j] += __shfl_xor(acc[j], off);

    float v[4];
    float m = -INFINITY;
    if (lane < 16 && act) {
        const float4 b = *((const float4*)bias + c);
        v[0] = acc[0] + b.x; v[1] = acc[1] + b.y;
        v[2] = acc[2] + b.z; v[3] = acc[3] + b.w;
        m = fmaxf(fmaxf(v[0], v[1]), fmaxf(v[2], v[3]));
    }
#pragma unroll
    for (int off = 32; off; off >>= 1) m = fmaxf(m, __shfl_xor(m, off));
    float ex = 0.f;
    if (lane < 16 && act)
        ex = expf(v[0] - m) + expf(v[1] - m) + expf(v[2] - m) + expf(v[3] - m);
#pragma unroll
    for (int off = 32; off; off >>= 1) ex += __shfl_xor(ex, off);
    float ls = logf(ex);
    if (lane < 16 && act) {
        float4 o;
        o.x = v[0] - m - ls; o.y = v[1] - m - ls;
        o.z = v[2] - m - ls; o.w = v[3] - m - ls;
        *(float4*)(out + (size_t)n * 40 + c * 4) = o;
    }
}

// ---------------- launch ----------------

extern "C" void kernel_launch(void* const* d_in, const int* in_sizes, int n_in,
                              void* d_out, int out_size, void* d_ws, size_t ws_size,
                              hipStream_t stream) {
    const float* x  = (const float*)d_in[0];
    const int*   ei = (const int*)d_in[1];
    const float* W1 = (const float*)d_in[2];
    const float* b1 = (const float*)d_in[3];
    const float* W2 = (const float*)d_in[4];
    const float* b2 = (const float*)d_in[5];
    const float* W3 = (const float*)d_in[6];
    const float* b3 = (const float*)d_in[7];
    const int N = in_sizes[0] / 512;
    const int E = in_sizes[1] / 2;
    const int* row = ei;
    const int* col = ei + E;

    char* p = (char*)d_ws;
    auto alloc = [&](size_t bytes) {
        void* r = (void*)p;
        p += (bytes + 255) & ~(size_t)255;
        return r;
    };
    float* dis    = (float*)alloc((size_t)N * 4);
    int*   cnt    = (int*)alloc((size_t)N * 4);
    int*   ptr    = (int*)alloc((size_t)(N + 1) * 4);
    int*   slot   = (int*)alloc((size_t)E * 4);
    int*   bsums  = (int*)alloc(1024);
    uint2* csr_en = (uint2*)alloc((size_t)E * 8);
    unsigned short* Wf1 = (unsigned short*)alloc(4 * 16 * 64 * 8 * 2);
    unsigned short* Wf2 = (unsigned short*)alloc(8 * 2 * 64 * 8 * 2);
    unsigned short* Wf3 = (unsigned short*)alloc(3 * 4 * 64 * 8 * 2);
    unsigned short* xw1 = (unsigned short*)alloc((size_t)N * 64 * 2);
    unsigned short* h1  = (unsigned short*)alloc((size_t)N * 64 * 2);
    unsigned short* a2  = (unsigned short*)alloc((size_t)N * 64 * 2);
    unsigned short* xw3 = (unsigned short*)alloc((size_t)N * 40 * 2);
    float* out = (float*)d_out;

    // prep: W fragments + zero cnt
    prep_kernel<<<(2 * N + 255) / 256, 256, 0, stream>>>(W1, W2, W3, Wf1, Wf2, Wf3, cnt, N);

    const int cgrid = (E + 255) / 256;
    countslot_kernel<<<cgrid, 256, 0, stream>>>(col, cnt, slot, E);

    // gemm1: LDS-staged coalesced (~39us, near HBM floor)
    const int ggrid = (N + 63) / 64;
    gemm1_kernel<<<ggrid, 256, 0, stream>>>(x, Wf1, xw1, N);

    // scan + dis + fill (atomic-free)
    int nb = (N + 1023) / 1024;
    scan1_kernel<<<nb, 1024, 0, stream>>>(cnt, ptr, bsums, N);
    scan2_kernel<<<1, 128, 0, stream>>>(bsums, nb);
    scan3d_kernel<<<nb, 1024, 0, stream>>>(ptr, bsums, cnt, dis, N, E);
    fill_kernel<<<cgrid, 256, 0, stream>>>(row, col, ptr, slot, dis, csr_en, E);

    const int ngrid2 = (N + 7) / 8;     // 2 nodes per wave
    const int ngrid  = (N + 3) / 4;

    // h1 = relu(Ahat xw1 + b1)
    agg64_kernel<true><<<ngrid2, 256, 0, stream>>>((const unsigned int*)xw1, b1, ptr, csr_en,
                                                   (unsigned int*)h1, N);
    // a2 = Ahat h1 ; xw3 = relu(a2 W2 + b2) W3
    agg64_kernel<false><<<ngrid2, 256, 0, stream>>>((const unsigned int*)h1, nullptr, ptr, csr_en,
                                                    (unsigned int*)a2, N);
    gemm23_kernel<<<ggrid, 256, 0, stream>>>(a2, Wf2, b2, Wf3, xw3, N);
    // out = log_softmax(Ahat xw3 + b3)
    agg40lsm_kernel<<<ngrid, 256, 0, stream>>>((const unsigned int*)xw3, b3, ptr, csr_en, out, N);
}